// Round 6
// baseline (589.047 us; speedup 1.0000x reference)
//
#include <hip/hip_runtime.h>
#include <hip/hip_bf16.h>

typedef __bf16 bf16;
typedef __attribute__((ext_vector_type(8))) __bf16 bf16x8;
typedef __attribute__((ext_vector_type(4))) __bf16 bf16x4;
typedef __attribute__((ext_vector_type(4))) short s16x4;
typedef __attribute__((ext_vector_type(4))) float f32x4;

#define GLOBAL_AS __attribute__((address_space(1)))
#define LDS_AS __attribute__((address_space(3)))

constexpr int B_  = 16;
constexpr int N_  = 1024;
constexpr int D_  = 768;
constexpr int H_  = 12;
constexpr int P_  = 16;
constexpr int FF_ = 3072;
constexpr int BN_ = B_ * N_;          // 16384
constexpr int LP_ = 1088;             // padded key length (1040 -> 1088)
constexpr float EXPC_ = 0.18033688f;  // SCALE * log2(e), folded into Q

// ---------------------------------------------------------------------------
// fused: fp32->bf16 weight conversion (blocks 0..6911) + prompt K/V prep
// (blocks 6912..7103).
// ---------------------------------------------------------------------------
__global__ __launch_bounds__(256) void cvt_prep_kernel(
    const float* __restrict__ s0, const float* __restrict__ s1,
    const float* __restrict__ s2, const float* __restrict__ s3,
    bf16* __restrict__ d0, bf16* __restrict__ d1,
    bf16* __restrict__ d2, bf16* __restrict__ d3,
    const float* __restrict__ prompt, bf16* __restrict__ Kall,
    bf16* __restrict__ VTall)
{
    int t = threadIdx.x;
    if (blockIdx.x < 6912) {
        int i = (blockIdx.x * 256 + t) * 4;
        const float* s; bf16* d; int off;
        if (i < 1769472)      { s = s0; d = d0; off = i; }
        else if (i < 2359296) { s = s1; d = d1; off = i - 1769472; }
        else if (i < 4718592) { s = s2; d = d2; off = i - 2359296; }
        else                  { s = s3; d = d3; off = i - 4718592; }
        float4 f = *(const float4*)(s + off);
        bf16x4 o;
        o[0] = (bf16)f.x; o[1] = (bf16)f.y; o[2] = (bf16)f.z; o[3] = (bf16)f.w;
        *(bf16x4*)(d + off) = o;
        return;
    }
    int hb = blockIdx.x - 6912;     // b*12 + h
    int b = hb / 12, h = hb % 12;
    size_t kbase = (size_t)hb * LP_ * 64;
    size_t vbase = (size_t)hb * 64 * LP_;
    {
        int p = t >> 4, d0i = (t & 15) * 4;
        const float* src = prompt + (((size_t)(b * 2 + 0) * P_ + p) * H_ + h) * 64 + d0i;
        float4 f = *(const float4*)src;
        bf16x4 o4;
        o4[0] = (bf16)f.x; o4[1] = (bf16)f.y; o4[2] = (bf16)f.z; o4[3] = (bf16)f.w;
        *(bf16x4*)(Kall + kbase + (size_t)p * 64 + d0i) = o4;
    }
    {
        int d = t >> 2, p0 = (t & 3) * 4;
        bf16x4 o4;
#pragma unroll
        for (int j = 0; j < 4; j++)
            o4[j] = (bf16)prompt[(((size_t)(b * 2 + 1) * P_ + p0 + j) * H_ + h) * 64 + d];
        *(bf16x4*)(VTall + vbase + (size_t)d * LP_ + p0) = o4;
    }
    {
        bf16* kp = Kall + kbase + 1040 * 64 + (size_t)t * 12;
#pragma unroll
        for (int i = 0; i < 12; i++) kp[i] = (bf16)0.f;
        int d = t >> 2, j0 = (t & 3) * 12;
        bf16* vp = VTall + vbase + (size_t)d * LP_ + 1040 + j0;
#pragma unroll
        for (int i = 0; i < 12; i++) vp[i] = (bf16)0.f;
    }
}

// ---------------------------------------------------------------------------
// LayerNorm over D=768, one row per block -> bf16 (input fp32 or bf16)
// ---------------------------------------------------------------------------
template <typename T>
__global__ __launch_bounds__(256) void ln_kernel(
    const T* __restrict__ x, const float* __restrict__ g,
    const float* __restrict__ bta, bf16* __restrict__ out)
{
    int row = blockIdx.x;
    const T* xr = x + (size_t)row * D_;
    int t = threadIdx.x;
    float v[3];
    float s = 0.f, ss = 0.f;
#pragma unroll
    for (int i = 0; i < 3; i++) {
        v[i] = (float)xr[t + i * 256];
        s += v[i];
        ss += v[i] * v[i];
    }
#pragma unroll
    for (int o = 32; o > 0; o >>= 1) {
        s  += __shfl_down(s, o);
        ss += __shfl_down(ss, o);
    }
    __shared__ float red_s[4], red_ss[4];
    int w = t >> 6, lane = t & 63;
    if (lane == 0) { red_s[w] = s; red_ss[w] = ss; }
    __syncthreads();
    s  = red_s[0] + red_s[1] + red_s[2] + red_s[3];
    ss = red_ss[0] + red_ss[1] + red_ss[2] + red_ss[3];
    float mu = s * (1.f / 768.f);
    float var = ss * (1.f / 768.f) - mu * mu;
    float rstd = rsqrtf(var + 1e-5f);
#pragma unroll
    for (int i = 0; i < 3; i++) {
        int c = t + i * 256;
        out[(size_t)row * D_ + c] = (bf16)((v[i] - mu) * rstd * g[c] + bta[c]);
    }
}

// ---------------------------------------------------------------------------
// GEMM  C[M,N] = A[M,K] * Bt[N,K]^T  (+bias, epilogue variants)
// 128x128 tile, BK=32, single-barrier register-prefetch double buffer:
//   ds_write(prefetched regs) -> issue next global loads -> barrier ->
//   8x ds_read_b128 + 16 MFMA.  Barrier needs only lgkmcnt (loads are to
//   VGPRs), so no vmcnt(0) drain anywhere in the K-loop.
// XCD-ownership 1D swizzle: each XCD owns contiguous row-bands.
// Chunk swizzle c ^ ((r>>1)&3) keeps b128 writes/reads <=2-way (free).
// EPI: 1 = bias + res(bf16) -> fp32   (FC2 final)
//      2 = bias + QuickGELU -> bf16   (FC1)
//      3 = qkv scatter -> Q_all (pre-scaled by EXPC_) / K_all / VT_all
//      4 = bias + res(fp32) -> bf16   (proj -> x1)
// ---------------------------------------------------------------------------
template <int EPI>
__global__ __launch_bounds__(256, 4) void gemm_bt(
    const bf16* __restrict__ A, const bf16* __restrict__ Bt,
    const float* __restrict__ bias,
    const float* __restrict__ resF, const bf16* __restrict__ resB,
    float* __restrict__ outF, bf16* __restrict__ outB,
    bf16* __restrict__ Qall, bf16* __restrict__ Kall, bf16* __restrict__ VTall,
    int M, int N, int K)
{
    __shared__ bf16 As[2][128 * 32];
    __shared__ bf16 Bs[2][128 * 32];

    const int nb = gridDim.x;
    const int gx = N >> 7;                   // col tiles
    const int bid = blockIdx.x;
    const int tile = (bid & 7) * (nb >> 3) + (bid >> 3);
    const int rowBase = (tile / gx) * 128;
    const int colBase = (tile % gx) * 128;

    const int tid = threadIdx.x;
    const int w = tid >> 6, lane = tid & 63;
    const int wr = w >> 1, wc = w & 1;
    const int lrow = lane & 15, khalf = lane >> 4;

    // staging: thread t owns row sr = t>>1, k-chunk pair c0 = (t&1)*2
    const int sr = tid >> 1;
    const int c0 = (tid & 1) * 2;
    const int ssw = (sr >> 1) & 3;
    const int pL0 = sr * 32 + ((c0 ^ ssw) * 8);
    const int pL1 = sr * 32 + (((c0 + 1) ^ ssw) * 8);

    const bf16* ag = A + (size_t)(rowBase + sr) * K + c0 * 8;
    const bf16* bg = Bt + (size_t)(colBase + sr) * K + c0 * 8;

    f32x4 acc[4][4];
#pragma unroll
    for (int mi = 0; mi < 4; mi++)
#pragma unroll
        for (int ni = 0; ni < 4; ni++)
            acc[mi][ni] = (f32x4){0.f, 0.f, 0.f, 0.f};

    bf16x8 pa0 = *(const bf16x8*)(ag);
    bf16x8 pa1 = *(const bf16x8*)(ag + 8);
    bf16x8 pb0 = *(const bf16x8*)(bg);
    bf16x8 pb1 = *(const bf16x8*)(bg + 8);

#pragma unroll 2
    for (int k0 = 0; k0 < K; k0 += 32) {
        const int buf = (k0 >> 5) & 1;
        *(bf16x8*)(&As[buf][pL0]) = pa0;
        *(bf16x8*)(&As[buf][pL1]) = pa1;
        *(bf16x8*)(&Bs[buf][pL0]) = pb0;
        *(bf16x8*)(&Bs[buf][pL1]) = pb1;
        // prefetch next K-slab into registers (no LDS dependence)
        int kn = (k0 + 32 < K) ? (k0 + 32) : k0;
        pa0 = *(const bf16x8*)(ag + kn);
        pa1 = *(const bf16x8*)(ag + kn + 8);
        pb0 = *(const bf16x8*)(bg + kn);
        pb1 = *(const bf16x8*)(bg + kn + 8);
        __syncthreads();

        bf16x8 af[4], bfr[4];
#pragma unroll
        for (int mi = 0; mi < 4; mi++) {
            int rr = wr * 64 + mi * 16 + lrow;
            af[mi] = *(const bf16x8*)(&As[buf][rr * 32 + ((khalf ^ ((rr >> 1) & 3)) * 8)]);
        }
#pragma unroll
        for (int ni = 0; ni < 4; ni++) {
            int rr = wc * 64 + ni * 16 + lrow;
            bfr[ni] = *(const bf16x8*)(&Bs[buf][rr * 32 + ((khalf ^ ((rr >> 1) & 3)) * 8)]);
        }
#pragma unroll
        for (int mi = 0; mi < 4; mi++)
#pragma unroll
            for (int ni = 0; ni < 4; ni++)
                acc[mi][ni] = __builtin_amdgcn_mfma_f32_16x16x32_bf16(
                    af[mi], bfr[ni], acc[mi][ni], 0, 0, 0);
    }

    // epilogue: C layout col = lane&15, row = (lane>>4)*4 + reg
#pragma unroll
    for (int mi = 0; mi < 4; mi++) {
#pragma unroll
        for (int ni = 0; ni < 4; ni++) {
            int col = colBase + wc * 64 + ni * 16 + lrow;
            int row0 = rowBase + wr * 64 + mi * 16 + khalf * 4;
            float bv = bias[col];
            if constexpr (EPI == 3) {
                int sect = (col >= 1536) ? 2 : (col >= 768 ? 1 : 0);
                int hh = (col >> 6) - sect * 12;
                int dd = col & 63;
                int bb = row0 >> 10, n0 = row0 & 1023;
                size_t bh = (size_t)bb * 12 + hh;
                if (sect == 0) {
                    bf16* qp = Qall + (bh * 1024 + n0) * 64 + dd;
#pragma unroll
                    for (int r = 0; r < 4; r++)
                        qp[(size_t)r * 64] = (bf16)((acc[mi][ni][r] + bv) * EXPC_);
                } else if (sect == 1) {
                    bf16* kp = Kall + bh * (LP_ * 64) + (size_t)(16 + n0) * 64 + dd;
#pragma unroll
                    for (int r = 0; r < 4; r++)
                        kp[(size_t)r * 64] = (bf16)(acc[mi][ni][r] + bv);
                } else {
                    bf16x4 pv;
#pragma unroll
                    for (int r = 0; r < 4; r++)
                        pv[r] = (bf16)(acc[mi][ni][r] + bv);
                    *(bf16x4*)(VTall + bh * (64 * LP_) + (size_t)dd * LP_ + 16 + n0) = pv;
                }
            } else {
#pragma unroll
                for (int r = 0; r < 4; r++) {
                    size_t idx = (size_t)(row0 + r) * N + col;
                    float v = acc[mi][ni][r] + bv;
                    if constexpr (EPI == 1) {
                        outF[idx] = v + (float)resB[idx];
                    } else if constexpr (EPI == 2) {
                        outB[idx] = (bf16)(v / (1.f + __expf(-1.702f * v)));
                    } else {  // EPI == 4
                        outB[idx] = (bf16)(v + resF[idx]);
                    }
                }
            }
        }
    }
}

// ---------------------------------------------------------------------------
// Flash attention v3 ("register P"): 1536 blocks (XCD-swizzled), 4 waves,
// 32 q-rows/wave. S^T = K*Q^T (x32 MFMA); exp2 of the C-layout fragments is
// bit-exact the B-operand of 16x16x16 MFMA; O^T = VT*P^T from registers.
// K/V double-buffered in LDS with 72-elt padded rows.
// ---------------------------------------------------------------------------
__global__ __launch_bounds__(256, 3) void attn_kernel(
    const bf16* __restrict__ Qall, const bf16* __restrict__ Kall,
    const bf16* __restrict__ VTall, bf16* __restrict__ o)
{
    __shared__ bf16 Ks[2][64 * 72];
    __shared__ bf16 Vt[2][64 * 72];

    const int lid = blockIdx.x;
    const int xcd = lid & 7, slot = lid >> 3;
    const int hb = xcd * 24 + (slot >> 3);     // = b*12 + h
    const int qt = slot & 7;
    const int h = hb % 12, b = hb / 12;

    const int tid = threadIdx.x;
    const int w = tid >> 6, lane = tid & 63;
    const int lrow = lane & 15, q4 = lane >> 4;

    bf16x8 qf[2][2];
    {
        const bf16* qb = Qall + ((size_t)hb * 1024 + qt * 128 + w * 32 + lrow) * 64 + q4 * 8;
        qf[0][0] = *(const bf16x8*)(qb);
        qf[0][1] = *(const bf16x8*)(qb + 32);
        qf[1][0] = *(const bf16x8*)(qb + 16 * 64);
        qf[1][1] = *(const bf16x8*)(qb + 16 * 64 + 32);
    }

    f32x4 acc_o[4][2];
#pragma unroll
    for (int dj = 0; dj < 4; dj++)
#pragma unroll
        for (int mi = 0; mi < 2; mi++)
            acc_o[dj][mi] = (f32x4){0.f, 0.f, 0.f, 0.f};
    float lp[2] = {0.f, 0.f};

    const bf16* kg = Kall + (size_t)hb * LP_ * 64;
    const bf16* vg = VTall + (size_t)hb * 64 * LP_;
    const int r_ = tid >> 2;
    const int c_ = (tid & 3) * 16;

    bf16x8 k0 = *(const bf16x8*)(kg + (size_t)r_ * 64 + c_);
    bf16x8 k1 = *(const bf16x8*)(kg + (size_t)r_ * 64 + c_ + 8);
    bf16x8 v0 = *(const bf16x8*)(vg + (size_t)r_ * LP_ + c_);
    bf16x8 v1 = *(const bf16x8*)(vg + (size_t)r_ * LP_ + c_ + 8);

    for (int kt = 0; kt < 17; kt++) {
        bf16* ksb = &Ks[kt & 1][0];
        bf16* vtb = &Vt[kt & 1][0];
        *(bf16x8*)(ksb + r_ * 72 + c_)     = k0;
        *(bf16x8*)(ksb + r_ * 72 + c_ + 8) = k1;
        *(bf16x8*)(vtb + r_ * 72 + c_)     = v0;
        *(bf16x8*)(vtb + r_ * 72 + c_ + 8) = v1;
        __syncthreads();

        int nkt = (kt < 16) ? kt + 1 : 16;
        k0 = *(const bf16x8*)(kg + (size_t)nkt * 4096 + (size_t)r_ * 64 + c_);
        k1 = *(const bf16x8*)(kg + (size_t)nkt * 4096 + (size_t)r_ * 64 + c_ + 8);
        v0 = *(const bf16x8*)(vg + (size_t)r_ * LP_ + nkt * 64 + c_);
        v1 = *(const bf16x8*)(vg + (size_t)r_ * LP_ + nkt * 64 + c_ + 8);

        f32x4 st[4][2];
#pragma unroll
        for (int kb = 0; kb < 4; kb++)
#pragma unroll
            for (int mi = 0; mi < 2; mi++)
                st[kb][mi] = (f32x4){0.f, 0.f, 0.f, 0.f};
#pragma unroll
        for (int kb = 0; kb < 4; kb++) {
#pragma unroll
            for (int ks = 0; ks < 2; ks++) {
                bf16x8 kf = *(const bf16x8*)(ksb + (size_t)(kb * 16 + lrow) * 72 +
                                             ks * 32 + q4 * 8);
                st[kb][0] = __builtin_amdgcn_mfma_f32_16x16x32_bf16(kf, qf[0][ks], st[kb][0], 0, 0, 0);
                st[kb][1] = __builtin_amdgcn_mfma_f32_16x16x32_bf16(kf, qf[1][ks], st[kb][1], 0, 0, 0);
            }
        }

        s16x4 pfrag[4][2];
#pragma unroll
        for (int kb = 0; kb < 4; kb++) {
#pragma unroll
            for (int mi = 0; mi < 2; mi++) {
                float e0 = __builtin_amdgcn_exp2f(st[kb][mi][0]);
                float e1 = __builtin_amdgcn_exp2f(st[kb][mi][1]);
                float e2 = __builtin_amdgcn_exp2f(st[kb][mi][2]);
                float e3 = __builtin_amdgcn_exp2f(st[kb][mi][3]);
                if (kt < 16 || kb == 0)
                    lp[mi] += (e0 + e1) + (e2 + e3);
                bf16x4 pb;
                pb[0] = (bf16)e0; pb[1] = (bf16)e1; pb[2] = (bf16)e2; pb[3] = (bf16)e3;
                pfrag[kb][mi] = __builtin_bit_cast(s16x4, pb);
            }
        }

#pragma unroll
        for (int dj = 0; dj < 4; dj++) {
#pragma unroll
            for (int kb = 0; kb < 4; kb++) {
                bf16x4 vf = *(const bf16x4*)(vtb + (size_t)(dj * 16 + lrow) * 72 +
                                             kb * 16 + q4 * 4);
                s16x4 vfs = __builtin_bit_cast(s16x4, vf);
                acc_o[dj][0] = __builtin_amdgcn_mfma_f32_16x16x16bf16_1k(
                    vfs, pfrag[kb][0], acc_o[dj][0], 0, 0, 0);
                acc_o[dj][1] = __builtin_amdgcn_mfma_f32_16x16x16bf16_1k(
                    vfs, pfrag[kb][1], acc_o[dj][1], 0, 0, 0);
            }
        }
    }

    float linv[2];
#pragma unroll
    for (int mi = 0; mi < 2; mi++) {
        float ls = lp[mi];
        ls += __shfl_xor(ls, 16);
        ls += __shfl_xor(ls, 32);
        linv[mi] = 1.f / ls;
    }

    bf16* ob = o + (size_t)(b * N_ + qt * 128 + w * 32) * 768 + h * 64;
#pragma unroll
    for (int mi = 0; mi < 2; mi++) {
#pragma unroll
        for (int dj = 0; dj < 4; dj++) {
            bf16x4 ov;
#pragma unroll
            for (int r = 0; r < 4; r++)
                ov[r] = (bf16)(acc_o[dj][mi][r] * linv[mi]);
            *(bf16x4*)(ob + (size_t)(mi * 16 + lrow) * 768 + dj * 16 + q4 * 4) = ov;
        }
    }
}

// ---------------------------------------------------------------------------
extern "C" void kernel_launch(void* const* d_in, const int* in_sizes, int n_in,
                              void* d_out, int out_size, void* d_ws, size_t ws_size,
                              hipStream_t stream)
{
    const float* x      = (const float*)d_in[0];
    const float* prompt = (const float*)d_in[1];
    const float* qkv_w  = (const float*)d_in[2];
    const float* qkv_b  = (const float*)d_in[3];
    const float* out_w  = (const float*)d_in[4];
    const float* out_b  = (const float*)d_in[5];
    const float* ln1_g  = (const float*)d_in[6];
    const float* ln1_b  = (const float*)d_in[7];
    const float* ln2_g  = (const float*)d_in[8];
    const float* ln2_b  = (const float*)d_in[9];
    const float* fc1_w  = (const float*)d_in[10];
    const float* fc1_b  = (const float*)d_in[11];
    const float* fc2_w  = (const float*)d_in[12];
    const float* fc2_b  = (const float*)d_in[13];
    float* out = (float*)d_out;

    // workspace layout (bf16 elements)
    bf16* qkvw_b = (bf16*)d_ws;               // 1,769,472
    bf16* outw_b = qkvw_b + 1769472;          //   589,824
    bf16* fc1w_b = outw_b + 589824;           // 2,359,296
    bf16* fc2w_b = fc1w_b + 2359296;          // 2,359,296   (weights end 7,077,888)
    bf16* h_b    = fc2w_b + 2359296;          // 12,582,912
    bf16* o_b    = h_b    + 12582912;         // 12,582,912 ┐
    bf16* Qall   = o_b    + 12582912;         // 12,582,912 │ fc1-mid (50,331,648)
    bf16* Kall   = Qall   + 12582912;         // 13,369,344 │ aliases o_b..VT_all
    bf16* VTall  = Kall   + 13369344;         // 13,369,344 ┘ (dead by then)
    bf16* mid    = o_b;                       // 50,331,648 bf16
    bf16* x1b    = VTall + 13369344;          // 12,582,912 bf16 (x + attn)

    // 1. weight conversion + prompt prep (fused)
    cvt_prep_kernel<<<7104, 256, 0, stream>>>(qkv_w, out_w, fc1_w, fc2_w,
                                              qkvw_b, outw_b, fc1w_b, fc2w_b,
                                              prompt, Kall, VTall);
    // 2. LN1
    ln_kernel<float><<<BN_, 256, 0, stream>>>(x, ln1_g, ln1_b, h_b);
    // 3. QKV projection, scatter epilogue -> Q_all (pre-scaled) / K_all / VT_all
    gemm_bt<3><<<18 * 128, 256, 0, stream>>>(h_b, qkvw_b, qkv_b, nullptr, nullptr,
                                             nullptr, nullptr, Qall, Kall, VTall,
                                             BN_, 2304, 768);
    // 4. attention
    attn_kernel<<<1536, 256, 0, stream>>>(Qall, Kall, VTall, o_b);
    // 5. out projection + residual(x fp32) -> x1 (bf16)
    gemm_bt<4><<<6 * 128, 256, 0, stream>>>(o_b, outw_b, out_b, x, nullptr,
                                            nullptr, x1b, nullptr, nullptr, nullptr,
                                            BN_, 768, 768);
    // 6. LN2 (bf16 input)
    ln_kernel<bf16><<<BN_, 256, 0, stream>>>(x1b, ln2_g, ln2_b, h_b);
    // 7. FC1 + QuickGELU -> bf16 [BN,3072]
    gemm_bt<2><<<24 * 128, 256, 0, stream>>>(h_b, fc1w_b, fc1_b, nullptr, nullptr,
                                             nullptr, mid, nullptr, nullptr, nullptr,
                                             BN_, FF_, 768);
    // 8. FC2 + residual(x1b bf16) -> out (fp32)
    gemm_bt<1><<<6 * 128, 256, 0, stream>>>(mid, fc2w_b, fc2_b, nullptr, x1b,
                                            out, nullptr, nullptr, nullptr, nullptr,
                                            BN_, 768, FF_);
}